// Round 12
// baseline (171.962 us; speedup 1.0000x reference)
//
#include <hip/hip_runtime.h>

#define INF_F (__builtin_inff())
#define PMAX 512
#define NPART 256        // nodes per partition (partition = node >> 8)
#define MARKER 0xFFFFFFFFu
#define CSTRIDE 16       // pad global counters to one 64B line each

// new path config
#define GB 1024          // blocks for kH / kB
#define TB 1024          // threads for kB
#define THH 512          // threads for kH
#define LRECB 6252       // per-block LDS record capacity (uint2) >= 2*CE

// fallback (R11) config
#define G1 1024
#define BT 512
#define BT4 1024
#define LREC 9856

// ---------------- common helpers ----------------

__device__ __forceinline__ unsigned int enc_f(float f) {
    unsigned int u = __float_as_uint(f);
    return (u & 0x80000000u) ? ~u : (u | 0x80000000u);
}
__device__ __forceinline__ float dec_f(unsigned int u) {
    unsigned int b = (u & 0x80000000u) ? (u & 0x7FFFFFFFu) : ~u;
    return __uint_as_float(b);
}
__device__ __forceinline__ float inv_clean(float x) {
    float r = 1.0f / x;
    if (isnan(r) || r == INF_F) r = 1.0f;
    return r;
}
__device__ __forceinline__ float edge_final(float ev, float c, float lw, float lb) {
    float ec = (isnan(ev) || ev == INF_F) ? 1.0f : ev;
    float out = ec * lw + lb + c * ec;
    if (out == INF_F) out = 1.0f;
    return out;
}
__device__ __forceinline__ float dot16_bias(const float* __restrict__ edge_attr,
                                            const float* __restrict__ lin_e_w,
                                            const float* __restrict__ lin_e_b, int e) {
    const float4* ea = reinterpret_cast<const float4*>(edge_attr) + (size_t)e * 4;
    const float4* w4 = reinterpret_cast<const float4*>(lin_e_w);
    float4 a0 = ea[0], a1 = ea[1], a2 = ea[2], a3 = ea[3];
    float4 w0 = w4[0], w1 = w4[1], w2 = w4[2], w3 = w4[3];
    return a0.x * w0.x + a0.y * w0.y + a0.z * w0.z + a0.w * w0.w
         + a1.x * w1.x + a1.y * w1.y + a1.z * w1.z + a1.w * w1.w
         + a2.x * w2.x + a2.y * w2.y + a2.z * w2.z + a2.w * w2.w
         + a3.x * w3.x + a3.y * w3.y + a3.z * w3.z + a3.w * w3.w
         + lin_e_b[0];
}

// ---------------- NEW PATH: reservation-based sort ----------------

// Z: zero the line-padded partition totals.
__global__ void kz_zero(unsigned int* __restrict__ gtotal, int P) {
    int t = threadIdx.x;
    if (t < P) gtotal[t * CSTRIDE] = 0u;
}

// H: per-partition totals from adjs only (LDS hist, then 1 global add per
// (block,partition) to a line-padded counter).
__global__ void __launch_bounds__(THH)
kh_hist(const int* __restrict__ src, const int* __restrict__ dst,
        unsigned int* __restrict__ gtotal, int E, int P, int CE) {
    __shared__ unsigned int hist[PMAX];
    int t = threadIdx.x, b = blockIdx.x;
    for (int p = t; p < P; p += THH) hist[p] = 0u;
    __syncthreads();
    int start = b * CE, end = min(E, start + CE);
    for (int e = start + t; e < end; e += THH) {
        atomicAdd(&hist[(unsigned int)src[e] >> 8], 1u);
        atomicAdd(&hist[(unsigned int)dst[e] >> 8], 1u);
    }
    __syncthreads();
    for (int p = t; p < P; p += THH)
        if (hist[p]) atomicAdd(&gtotal[p * CSTRIDE], hist[p]);
}

// S: one block. pbase = exclusive scan of per-partition worst-case allowance
// (total rounded to 8, + 7 pad slots per contributing block); init cursors.
__global__ void __launch_bounds__(512)
ks_scan(const unsigned int* __restrict__ gtotal, unsigned int* __restrict__ pbase,
        unsigned int* __restrict__ gcur, int P) {
    __shared__ unsigned int sc[512];
    int t = threadIdx.x;
    unsigned int v = 0u;
    if (t < P) v = ((gtotal[t * CSTRIDE] + 7u) & ~7u) + 7u * GB;  // 7*GB mult of 8
    sc[t] = v;
    __syncthreads();
    for (int off = 1; off < 512; off <<= 1) {
        unsigned int x = (t >= off) ? sc[t - off] : 0u;
        __syncthreads();
        sc[t] += x;
        __syncthreads();
    }
    if (t < P) {
        unsigned int excl = sc[t] - v;
        pbase[t] = excl;
        gcur[t * CSTRIDE] = excl;
    }
}

// B: the single heavy pass. Compute ev (write to d_out), bin records in LDS
// by partition, reserve [base,base+pad8(cnt)) per partition via ONE global
// atomic, copy runs out coalesced (markers fill the pad tail).
__global__ void __launch_bounds__(TB)
kb_ev_stage(const float* __restrict__ edge_attr,
            const int* __restrict__ src, const int* __restrict__ dst,
            const float* __restrict__ lin_e_w, const float* __restrict__ lin_e_b,
            float* __restrict__ ev_out, unsigned int* __restrict__ gcur,
            uint2* __restrict__ rec, int E, int P, int CE) {
    __shared__ uint2 lrec[LRECB];
    __shared__ unsigned int sc[512];
    __shared__ unsigned int lcnt[PMAX], lstart[PMAX], lcur[PMAX], lgb[PMAX];

    const int t = threadIdx.x, b = blockIdx.x;
    const int start = b * CE, end = min(E, start + CE);

    for (int p = t; p < P; p += TB) lcnt[p] = 0u;
    __syncthreads();

    // 1. load edges, compute ev, local hist (edge data stays in registers)
    int es[4], ed[4];
    float ee[4];
    #pragma unroll
    for (int i = 0; i < 4; ++i) {
        int e = start + i * TB + t;
        int s = 0, d = 0; float ev = 0.0f;
        if (e < end) {
            s = src[e]; d = dst[e];
            ev = dot16_bias(edge_attr, lin_e_w, lin_e_b, e);
            ev_out[e] = ev;
            atomicAdd(&lcnt[(unsigned int)s >> 8], 1u);
            atomicAdd(&lcnt[(unsigned int)d >> 8], 1u);
        }
        es[i] = s; ed[i] = d; ee[i] = ev;
    }
    __syncthreads();

    // 2. exclusive scan of lcnt -> lstart (first 512 threads; P <= 512)
    unsigned int v = (t < 512) ? ((t < P) ? lcnt[t] : 0u) : 0u;
    if (t < 512) sc[t] = v;
    __syncthreads();
    for (int off = 1; off < 512; off <<= 1) {
        unsigned int x = 0u;
        if (t < 512 && t >= off) x = sc[t - off];
        __syncthreads();
        if (t < 512) sc[t] += x;
        __syncthreads();
    }
    if (t < P) { lstart[t] = sc[t] - v; lcur[t] = sc[t] - v; }
    __syncthreads();

    // 3. reserve global runs (1 atomic per non-empty partition; latency
    //    hides under the LDS scatter below)
    if (t < P && lcnt[t])
        lgb[t] = atomicAdd(&gcur[t * CSTRIDE], (lcnt[t] + 7u) & ~7u);

    // 4. LDS scatter
    #pragma unroll
    for (int i = 0; i < 4; ++i) {
        int e = start + i * TB + t;
        if (e < end) {
            unsigned int ebits = __float_as_uint(ee[i]);
            unsigned int s = (unsigned int)es[i], d = (unsigned int)ed[i];
            unsigned int pos = atomicAdd(&lcur[d >> 8], 1u);
            lrec[pos] = make_uint2(ebits, d & 255u);
            pos = atomicAdd(&lcur[s >> 8], 1u);
            lrec[pos] = make_uint2(ebits, s & 255u);
        }
    }
    __syncthreads();

    // 5. coalesced copy-out: wave w handles partitions w, w+16, ...
    const int wv = t >> 6, lane = t & 63;
    for (int p = wv; p < P; p += TB / 64) {
        unsigned int rcnt = lcnt[p];
        if (!rcnt) continue;
        unsigned int base = lgb[p], ls = lstart[p];
        unsigned int padded = (rcnt + 7u) & ~7u;
        for (unsigned int j = lane; j < padded; j += 64)
            rec[base + j] = (j < rcnt) ? lrec[ls + j] : make_uint2(0u, MARKER);
    }
}

// R: per-partition reduce; contiguous uint4 sweep of [pbase, gcur_final).
__global__ void __launch_bounds__(1024)
kr_reduce(const uint2* __restrict__ rec,
          const unsigned int* __restrict__ pbase, const unsigned int* __restrict__ gcur,
          const float* __restrict__ aggr2_w, const float* __restrict__ aggr2_b,
          float* __restrict__ nodeC, int N) {
    __shared__ float ssum[NPART];
    __shared__ unsigned int scnt[NPART], smax[NPART], smin[NPART];
    int p = blockIdx.x, t = threadIdx.x;
    if (t < NPART) { ssum[t] = 0.0f; scnt[t] = 0u; smax[t] = 0u; smin[t] = 0xFFFFFFFFu; }
    __syncthreads();
    unsigned int pb = pbase[p];
    unsigned int pe = gcur[p * CSTRIDE];           // both multiples of 8
    const uint4* r4 = reinterpret_cast<const uint4*>(rec + pb);
    unsigned int n4 = (pe - pb) >> 1;              // 2 records per uint4
    for (unsigned int i = t; i < n4; i += 1024) {
        uint4 q = r4[i];
        if (q.y != MARKER) {
            float v = __uint_as_float(q.x);
            unsigned int eu = enc_f(v);
            atomicAdd(&ssum[q.y], v);
            atomicAdd(&scnt[q.y], 1u);
            atomicMax(&smax[q.y], eu);
            atomicMin(&smin[q.y], eu);
        }
        if (q.w != MARKER) {
            float v = __uint_as_float(q.z);
            unsigned int eu = enc_f(v);
            atomicAdd(&ssum[q.w], v);
            atomicAdd(&scnt[q.w], 1u);
            atomicMax(&smax[q.w], eu);
            atomicMin(&smin[q.w], eu);
        }
    }
    __syncthreads();
    int node = p * NPART + t;
    if (t < NPART && node < N) {
        unsigned int c = scnt[t];
        float sum = ssum[t];
        float mxv = (c > 0u) ? dec_f(smax[t]) : 0.0f;
        float mnv = (c > 0u) ? dec_f(smin[t]) : 0.0f;
        float mean = sum / fmaxf((float)c, 1.0f);
        float4 w = *reinterpret_cast<const float4*>(aggr2_w);
        nodeC[node] = w.x * inv_clean(mxv) + w.y * inv_clean(mean)
                    + w.z * inv_clean(mnv) + w.w * inv_clean(sum) + aggr2_b[0];
    }
}

// K6: final edge pass. ev lives in d_out; in-place elementwise rewrite.
__global__ void __launch_bounds__(256)
edge_out(float* __restrict__ evout, const int* __restrict__ dst,
         const float* __restrict__ nodeC,
         const float* __restrict__ lin_l_w, const float* __restrict__ lin_l_b,
         int E) {
    int i = blockIdx.x * blockDim.x + threadIdx.x;
    int base = i * 4;
    float lw = lin_l_w[0], lb = lin_l_b[0];
    if (base + 3 < E) {
        float4 ev = *reinterpret_cast<const float4*>(evout + base);
        int4 d = *reinterpret_cast<const int4*>(dst + base);
        float4 o;
        o.x = edge_final(ev.x, nodeC[d.x], lw, lb);
        o.y = edge_final(ev.y, nodeC[d.y], lw, lb);
        o.z = edge_final(ev.z, nodeC[d.z], lw, lb);
        o.w = edge_final(ev.w, nodeC[d.w], lw, lb);
        *reinterpret_cast<float4*>(evout + base) = o;
    } else {
        for (int e = base; e < E; ++e)
            evout[e] = edge_final(evout[e], nodeC[dst[e]], lw, lb);
    }
}

// ---------------- FALLBACK: R11 pipeline (proven, 167 us) ----------------

__global__ void __launch_bounds__(BT)
k1_ev_count(const float* __restrict__ edge_attr,
            const int* __restrict__ src, const int* __restrict__ dst,
            const float* __restrict__ lin_e_w, const float* __restrict__ lin_e_b,
            float* __restrict__ ev_out, unsigned int* __restrict__ gh,
            int E, int P, int CE) {
    __shared__ unsigned int hist[PMAX];
    int t = threadIdx.x, b = blockIdx.x;
    for (int p = t; p < P; p += BT) hist[p] = 0u;
    __syncthreads();
    int start = b * CE, end = min(E, start + CE);
    for (int e = start + t; e < end; e += BT) {
        float ev = dot16_bias(edge_attr, lin_e_w, lin_e_b, e);
        ev_out[e] = ev;
        atomicAdd(&hist[(unsigned int)src[e] >> 8], 1u);
        atomicAdd(&hist[(unsigned int)dst[e] >> 8], 1u);
    }
    __syncthreads();
    for (int p = t; p < P; p += BT) gh[(size_t)b * P + p] = hist[p];
}

__global__ void __launch_bounds__(256)
k2_scan_cols(unsigned int* __restrict__ gh, unsigned int* __restrict__ ptotal, int P) {
    const int VPT = G1 / 256;
    int p = blockIdx.x, t = threadIdx.x;
    unsigned int v[VPT], s = 0u;
    #pragma unroll
    for (int i = 0; i < VPT; ++i) {
        v[i] = (gh[(size_t)(t * VPT + i) * P + p] + 7u) & ~7u;
        s += v[i];
    }
    __shared__ unsigned int sc[256];
    sc[t] = s;
    __syncthreads();
    for (int off = 1; off < 256; off <<= 1) {
        unsigned int x = (t >= off) ? sc[t - off] : 0u;
        __syncthreads();
        sc[t] += x;
        __syncthreads();
    }
    unsigned int run = sc[t] - s;
    #pragma unroll
    for (int i = 0; i < VPT; ++i) {
        gh[(size_t)(t * VPT + i) * P + p] = run;
        run += v[i];
    }
    if (t == 255) ptotal[p] = run;
}

__global__ void k3_scan_part(const unsigned int* __restrict__ ptotal,
                             unsigned int* __restrict__ pbase, int P) {
    int t = threadIdx.x;
    unsigned int u0 = (2 * t < P) ? ptotal[2 * t] : 0u;
    unsigned int u1 = (2 * t + 1 < P) ? ptotal[2 * t + 1] : 0u;
    unsigned int s = u0 + u1;
    __shared__ unsigned int sc[256];
    sc[t] = s;
    __syncthreads();
    for (int off = 1; off < 256; off <<= 1) {
        unsigned int x = (t >= off) ? sc[t - off] : 0u;
        __syncthreads();
        sc[t] += x;
        __syncthreads();
    }
    unsigned int excl = sc[t] - s;
    if (2 * t < P) pbase[2 * t] = excl;
    if (2 * t + 1 < P) pbase[2 * t + 1] = excl + u0;
}

__global__ void __launch_bounds__(BT4)
k4_staged(const int* __restrict__ src, const int* __restrict__ dst,
          const float* __restrict__ ev_in,
          const unsigned int* __restrict__ gh, const unsigned int* __restrict__ pbase,
          const unsigned int* __restrict__ ptotal,
          uint2* __restrict__ rec, int E, int P, int CE) {
    __shared__ uint2 lrec[LREC];
    __shared__ unsigned int lstart[PMAX + 1];
    __shared__ unsigned int lcur[PMAX];
    __shared__ unsigned int goff[PMAX];
    __shared__ unsigned int sc[512];

    const int t = threadIdx.x, b = blockIdx.x;
    for (int p = t; p < P; p += BT4) {
        unsigned int g0 = gh[(size_t)b * P + p];
        unsigned int g1 = (b + 1 < G1) ? gh[(size_t)(b + 1) * P + p] : ptotal[p];
        lcur[p] = g1 - g0;
        goff[p] = pbase[p] + g0;
    }
    __syncthreads();
    unsigned int v = (t < P) ? lcur[t] : 0u;
    if (t < 512) sc[t] = v;
    __syncthreads();
    for (int off = 1; off < 512; off <<= 1) {
        unsigned int x = 0u;
        if (t < 512 && t >= off) x = sc[t - off];
        __syncthreads();
        if (t < 512) sc[t] += x;
        __syncthreads();
    }
    if (t < P) { lstart[t] = sc[t] - v; lcur[t] = sc[t] - v; }
    if (t == P - 1) lstart[P] = sc[t];
    __syncthreads();
    const int start = b * CE, end = min(E, start + CE);
    for (int e = start + t; e < end; e += BT4) {
        float ev = ev_in[e];
        unsigned int ebits = __float_as_uint(ev);
        unsigned int s = (unsigned int)src[e], d = (unsigned int)dst[e];
        unsigned int pos = atomicAdd(&lcur[d >> 8], 1u);
        lrec[pos] = make_uint2(ebits, d & 255u);
        pos = atomicAdd(&lcur[s >> 8], 1u);
        lrec[pos] = make_uint2(ebits, s & 255u);
    }
    __syncthreads();
    for (int p = t; p < P; p += BT4)
        for (unsigned int q = lcur[p]; q < lstart[p + 1]; ++q)
            lrec[q] = make_uint2(0u, MARKER);
    __syncthreads();
    const unsigned int tot = lstart[P];
    for (unsigned int j = t; j < tot; j += BT4) {
        int lo = 0, hi = P;
        while (hi - lo > 1) {
            int mid = (lo + hi) >> 1;
            if (lstart[mid] <= j) lo = mid; else hi = mid;
        }
        rec[goff[lo] + (j - lstart[lo])] = lrec[j];
    }
}

__global__ void __launch_bounds__(1024)
k5_reduce(const uint2* __restrict__ rec,
          const unsigned int* __restrict__ pbase, const unsigned int* __restrict__ ptotal,
          const float* __restrict__ aggr2_w, const float* __restrict__ aggr2_b,
          float* __restrict__ nodeC, int N) {
    __shared__ float ssum[NPART];
    __shared__ unsigned int scnt[NPART], smax[NPART], smin[NPART];
    int p = blockIdx.x, t = threadIdx.x;
    if (t < NPART) { ssum[t] = 0.0f; scnt[t] = 0u; smax[t] = 0u; smin[t] = 0xFFFFFFFFu; }
    __syncthreads();
    unsigned int pb = pbase[p], tot = ptotal[p];
    const uint4* r4 = reinterpret_cast<const uint4*>(rec + pb);
    unsigned int n4 = tot >> 1;
    for (unsigned int i = t; i < n4; i += 1024) {
        uint4 q = r4[i];
        if (q.y != MARKER) {
            float v = __uint_as_float(q.x);
            unsigned int eu = enc_f(v);
            atomicAdd(&ssum[q.y], v);
            atomicAdd(&scnt[q.y], 1u);
            atomicMax(&smax[q.y], eu);
            atomicMin(&smin[q.y], eu);
        }
        if (q.w != MARKER) {
            float v = __uint_as_float(q.z);
            unsigned int eu = enc_f(v);
            atomicAdd(&ssum[q.w], v);
            atomicAdd(&scnt[q.w], 1u);
            atomicMax(&smax[q.w], eu);
            atomicMin(&smin[q.w], eu);
        }
    }
    __syncthreads();
    int node = p * NPART + t;
    if (t < NPART && node < N) {
        unsigned int c = scnt[t];
        float sum = ssum[t];
        float mxv = (c > 0u) ? dec_f(smax[t]) : 0.0f;
        float mnv = (c > 0u) ? dec_f(smin[t]) : 0.0f;
        float mean = sum / fmaxf((float)c, 1.0f);
        float4 w = *reinterpret_cast<const float4*>(aggr2_w);
        nodeC[node] = w.x * inv_clean(mxv) + w.y * inv_clean(mean)
                    + w.z * inv_clean(mnv) + w.w * inv_clean(sum) + aggr2_b[0];
    }
}

static inline size_t align64(size_t x) { return (x + 63) & ~(size_t)63; }

extern "C" void kernel_launch(void* const* d_in, const int* in_sizes, int n_in,
                              void* d_out, int out_size, void* d_ws, size_t ws_size,
                              hipStream_t stream) {
    const int N = in_sizes[0] / 8;   // x: [N,8] (x otherwise unused)
    const int E = in_sizes[1] / 2;   // adjs: [2,E]

    const int*   adjs      = (const int*)d_in[1];
    const int*   src       = adjs;
    const int*   dst       = adjs + E;
    const float* edge_attr = (const float*)d_in[2];
    const float* lin_e_w   = (const float*)d_in[3];
    const float* lin_e_b   = (const float*)d_in[4];
    const float* aggr2_w   = (const float*)d_in[5];
    const float* aggr2_b   = (const float*)d_in[6];
    const float* lin_l_w   = (const float*)d_in[7];
    const float* lin_l_b   = (const float*)d_in[8];
    float* out = (float*)d_out;      // also holds ev between stage and k6

    char* ws = (char*)d_ws;
    const int P = (N + NPART - 1) / NPART;

    // ---- new reservation path ----
    const int CEb = (E + GB - 1) / GB;
    size_t rec_cap = (size_t)2 * E + (size_t)P * (7u * GB + 8u) + 64;
    size_t n_gt = 0;
    size_t n_pb = align64(n_gt + (size_t)PMAX * CSTRIDE * 4);
    size_t n_gc = align64(n_pb + (size_t)PMAX * 4);
    size_t n_rc = align64(n_gc + (size_t)PMAX * CSTRIDE * 4);
    size_t n_nc = align64(n_rc + rec_cap * 8);
    size_t need_new = n_nc + (size_t)N * 4;

    if (P <= PMAX && 2 * CEb <= LRECB && ws_size >= need_new) {
        unsigned int* gtotal = (unsigned int*)(ws + n_gt);
        unsigned int* pbase  = (unsigned int*)(ws + n_pb);
        unsigned int* gcur   = (unsigned int*)(ws + n_gc);
        uint2*        rec    = (uint2*)(ws + n_rc);
        float*        nodeC  = (float*)(ws + n_nc);

        const int CEh = (E + GB - 1) / GB;
        hipLaunchKernelGGL(kz_zero, dim3(1), dim3(512), 0, stream, gtotal, P);
        hipLaunchKernelGGL(kh_hist, dim3(GB), dim3(THH), 0, stream,
                           src, dst, gtotal, E, P, CEh);
        hipLaunchKernelGGL(ks_scan, dim3(1), dim3(512), 0, stream,
                           gtotal, pbase, gcur, P);
        hipLaunchKernelGGL(kb_ev_stage, dim3(GB), dim3(TB), 0, stream,
                           edge_attr, src, dst, lin_e_w, lin_e_b,
                           out, gcur, rec, E, P, CEb);
        hipLaunchKernelGGL(kr_reduce, dim3(P), dim3(1024), 0, stream,
                           rec, pbase, gcur, aggr2_w, aggr2_b, nodeC, N);
        int nt = (E + 3) / 4;
        hipLaunchKernelGGL(edge_out, dim3((nt + 255) / 256), dim3(256), 0, stream,
                           out, dst, nodeC, lin_l_w, lin_l_b, E);
        return;
    }

    // ---- fallback: R11 pipeline ----
    const int CE = (E + G1 - 1) / G1;
    size_t max_rec = (size_t)2 * E + (size_t)G1 * P * 8;
    size_t off_gh = 0;
    size_t off_pt = align64(off_gh + (size_t)G1 * P * 4);
    size_t off_pb = align64(off_pt + (size_t)PMAX * 4);
    size_t off_rc = align64(off_pb + (size_t)PMAX * 4);
    size_t off_nc = align64(off_rc + max_rec * 8);

    unsigned int* gh     = (unsigned int*)(ws + off_gh);
    unsigned int* ptotal = (unsigned int*)(ws + off_pt);
    unsigned int* pbase  = (unsigned int*)(ws + off_pb);
    uint2*        rec    = (uint2*)(ws + off_rc);
    float*        nodeC  = (float*)(ws + off_nc);

    hipLaunchKernelGGL(k1_ev_count, dim3(G1), dim3(BT), 0, stream,
                       edge_attr, src, dst, lin_e_w, lin_e_b, out, gh, E, P, CE);
    hipLaunchKernelGGL(k2_scan_cols, dim3(P), dim3(256), 0, stream, gh, ptotal, P);
    hipLaunchKernelGGL(k3_scan_part, dim3(1), dim3(256), 0, stream, ptotal, pbase, P);
    hipLaunchKernelGGL(k4_staged, dim3(G1), dim3(BT4), 0, stream,
                       src, dst, out, gh, pbase, ptotal, rec, E, P, CE);
    hipLaunchKernelGGL(k5_reduce, dim3(P), dim3(1024), 0, stream,
                       rec, pbase, ptotal, aggr2_w, aggr2_b, nodeC, N);
    int nt = (E + 3) / 4;
    hipLaunchKernelGGL(edge_out, dim3((nt + 255) / 256), dim3(256), 0, stream,
                       out, dst, nodeC, lin_l_w, lin_l_b, E);
}